// Round 10
// baseline (203.684 us; speedup 1.0000x reference)
//
#include <hip/hip_runtime.h>
#include <hip/hip_bf16.h>
#include <math.h>

#define N_USERS 8192
#define DIMS    128
#define EDGES   262144
#define KCAND   131072
#define NTOT    (EDGES + KCAND)      // 393216
#define LISTCAP 131072
#define CAPB    512                  // per-tile LDS staging capacity (entries)
#define NTILES  2080                 // triangular 64x64 tiles of 128x128
#define COS_THR 0.3f
#define EPS_SEL 6e-3f                // > hard error bound ~4e-3 of bf16 cos
#define LOGIT_MARGIN 2e-3f
#define DEADKEY 0xFFFFFFFFu

typedef short bf16x8 __attribute__((ext_vector_type(8)));
typedef float f32x4  __attribute__((ext_vector_type(4)));

// ---------------------------------------------------------------------------
// 1) prep (fused): blocks 0..31 -> normalize (bit-exact vs numpy) + bf16 copy
//    + per-user partial logits; blocks 32..1055 -> exclusion bitmask.
// ---------------------------------------------------------------------------
__global__ __launch_bounds__(256) void prep_k(const float* __restrict__ x,
                                              const float* __restrict__ W,
                                              const int* __restrict__ nz,
                                              float* __restrict__ un,
                                              unsigned short* __restrict__ u0,
                                              float4* __restrict__ P,
                                              unsigned* __restrict__ excl) {
  if (blockIdx.x < 32) {
#pragma clang fp contract(off)
    int i = blockIdx.x * 256 + threadIdx.x;
    const float* r = x + (size_t)i * DIMS;
    float a[8];
#pragma unroll
    for (int j = 0; j < 8; ++j) { float t = r[j]; a[j] = t * t; }
    for (int b8 = 8; b8 < DIMS; b8 += 8) {
#pragma unroll
      for (int j = 0; j < 8; ++j) { float t = r[b8 + j]; a[j] = a[j] + t * t; }
    }
    float s = ((a[0] + a[1]) + (a[2] + a[3])) + ((a[4] + a[5]) + (a[6] + a[7]));
    float n = (float)sqrt((double)s);
    n = fmaxf(n, 1e-12f);
    for (int k = 0; k < DIMS; ++k) {
      float t = r[k] / n;
      un[(size_t)i * DIMS + k] = t;
      __hip_bfloat16 h = __float2bfloat16(t);
      u0[(size_t)i * DIMS + k] = *(unsigned short*)&h;
    }
    float a0 = 0.f, b0 = 0.f, a1 = 0.f, b1 = 0.f;
    for (int k = 0; k < DIMS; ++k) {
      float t = r[k];
      a0 = fmaf(t, W[k], a0);
      b0 = fmaf(t, W[128 + k], b0);
      a1 = fmaf(t, W[256 + k], a1);
      b1 = fmaf(t, W[384 + k], b1);
    }
    P[i] = make_float4(a0, b0, a1, b1);
  } else {
    int t = (blockIdx.x - 32) * 256 + threadIdx.x;
    if (t < EDGES) {
      int i = nz[2 * t], j = nz[2 * t + 1];
      atomicOr(&excl[(size_t)i * 256 + (j >> 5)], 1u << (j & 31));
    }
  }
}

// ---------------------------------------------------------------------------
// 2) mfma_pass: PERSISTENT triangular sweep.  256 blocks (1/CU) x 512 thr;
//    each walks ~8 contiguous tiles in (bi,bj) lex order.  Double-buffered
//    B staging (prefetch next tile's B during current compute); A reloaded
//    only when bi changes.  R9 post-mortem: 2080 independent blocks paid
//    cold-load latency + flush serially (~51us, pipes idle); persistence
//    overlaps tile t+1's loads with tile t's compute.
//    LDS: As 32K + Bs 2x32K + svec 4K = ~101 KB -> 1 block/CU.
//    Wave tile 32x64, acc 32 VGPR (no-spill budget, R8/R9-verified).
//    Emit j>i + mirror; per-tile LDS list; one global atomicAdd per tile.
// ---------------------------------------------------------------------------
__global__ __launch_bounds__(512) void mfma_pass(const unsigned short* __restrict__ u0,
                                                 uint2* __restrict__ list,
                                                 int* __restrict__ gcount) {
  __shared__ __align__(16) unsigned short As[4][4][128][8];     // 32 KB
  __shared__ __align__(16) unsigned short Bs[2][4][4][128][8];  // 64 KB
  __shared__ uint2 svec[CAPB];                                  // 4 KB
  __shared__ int lcnt, lbase, sn;

  const int tid  = threadIdx.x;
  const int lane = tid & 63;
  const int wv   = tid >> 6;
  const int quad = lane >> 4;
  const int l15  = lane & 15;
  const int moff = (wv & 3) * 32, noff = (wv >> 2) * 64;

  const int start = (int)(((long)blockIdx.x * NTILES) >> 8);
  const int end   = (int)(((long)(blockIdx.x + 1) * NTILES) >> 8);

  int rem = start, bi = 0;
  while (rem >= 64 - bi) { rem -= 64 - bi; ++bi; }
  int bj = bi + rem;

  if (tid == 0) lcnt = 0;

  // initial A + B loads -> buffer 0
  uint4 pA[4], pB[4];
#pragma unroll
  for (int it = 0; it < 4; ++it) {
    int f = it * 512 + tid;
    int row = f & 127, cq = f >> 7;
    pA[it] = *(const uint4*)((const char*)u0 +
              (size_t)(bi * 128 + row) * 256 + cq * 16);
    pB[it] = *(const uint4*)((const char*)u0 +
              (size_t)(bj * 128 + row) * 256 + cq * 16);
  }
#pragma unroll
  for (int it = 0; it < 4; ++it) {
    ((uint4*)As)[it * 512 + tid] = pA[it];
    ((uint4*)(Bs[0]))[it * 512 + tid] = pB[it];
  }
  __syncthreads();

  int buf = 0;
#pragma unroll 1
  for (int t = start; t < end; ++t) {
    const int I0 = bi * 128, J0 = bj * 128;

    // next-tile coords + prefetch (loads land during current compute)
    int nbi = bi, nbj = bj + 1;
    if (nbj == 64) { nbi = bi + 1; nbj = nbi; }
    const bool havenext = (t + 1 < end);
    const bool aChange = havenext && (nbi != bi);
    if (havenext) {
#pragma unroll
      for (int it = 0; it < 4; ++it) {
        int f = it * 512 + tid;
        int row = f & 127, cq = f >> 7;
        pB[it] = *(const uint4*)((const char*)u0 +
                  (size_t)(nbj * 128 + row) * 256 + cq * 16);
      }
      if (aChange) {
#pragma unroll
        for (int it = 0; it < 4; ++it) {
          int f = it * 512 + tid;
          int row = f & 127, cq = f >> 7;
          pA[it] = *(const uint4*)((const char*)u0 +
                    (size_t)(nbi * 128 + row) * 256 + cq * 16);
        }
      }
    }

    // ---- compute: 4 kc x (2 af + 4 bfr b128 reads, 8 MFMAs) ----
    f32x4 acc[2][4];
#pragma unroll
    for (int mt = 0; mt < 2; ++mt)
#pragma unroll
      for (int nt = 0; nt < 4; ++nt)
#pragma unroll
        for (int g = 0; g < 4; ++g) acc[mt][nt][g] = 0.f;

#pragma unroll
    for (int kc = 0; kc < 4; ++kc) {
      bf16x8 af[2], bfr[4];
#pragma unroll
      for (int mt = 0; mt < 2; ++mt)
        af[mt] = *(const bf16x8*)&As[kc][quad][moff + mt * 16 + l15][0];
#pragma unroll
      for (int nt = 0; nt < 4; ++nt)
        bfr[nt] = *(const bf16x8*)&Bs[buf][kc][quad][noff + nt * 16 + l15][0];
#pragma unroll
      for (int mt = 0; mt < 2; ++mt)
#pragma unroll
        for (int nt = 0; nt < 4; ++nt)
          acc[mt][nt] = __builtin_amdgcn_mfma_f32_16x16x32_bf16(
              af[mt], bfr[nt], acc[mt][nt], 0, 0, 0);
    }

    // ---- epilogue: j > i; emit pair + mirror via LDS list ----
#pragma unroll
    for (int mt = 0; mt < 2; ++mt)
#pragma unroll
      for (int nt = 0; nt < 4; ++nt)
#pragma unroll
        for (int g = 0; g < 4; ++g) {
          float v = acc[mt][nt][g];
          if (v > COS_THR - EPS_SEL) {
            int i = I0 + moff + mt * 16 + quad * 4 + g;
            int j = J0 + noff + nt * 16 + l15;
            if (j > i) {
              int idx = atomicAdd(&lcnt, 2);
              if (idx + 1 < CAPB) {
                svec[idx]     = make_uint2(((unsigned)i << 13) | j,
                                           __float_as_uint(v));
                svec[idx + 1] = make_uint2(((unsigned)j << 13) | i,
                                           __float_as_uint(v));
              }
            }
          }
        }

    __syncthreads();   // appends done; As/Bs[buf] reads done
    if (tid == 0) { sn = min(lcnt, CAPB); lbase = atomicAdd(gcount, sn); }
    __syncthreads();
    int n = sn, base = lbase;
    for (int s2 = tid; s2 < n; s2 += 512) {
      int o = base + s2;
      if (o < LISTCAP) list[o] = svec[s2];
    }
    if (tid == 0) lcnt = 0;   // visible after the staging barrier below

    // ---- stage prefetched tile into the other buffer ----
    if (havenext) {
#pragma unroll
      for (int it = 0; it < 4; ++it)
        ((uint4*)(Bs[buf ^ 1]))[it * 512 + tid] = pB[it];
      if (aChange) {
#pragma unroll
        for (int it = 0; it < 4; ++it)
          ((uint4*)As)[it * 512 + tid] = pA[it];
      }
    }
    __syncthreads();   // staging visible + lcnt reset ordered
    buf ^= 1;
    bi = nbi; bj = nbj;
  }
}

// ---------------------------------------------------------------------------
// 3) resolve + histogram (fused)
// ---------------------------------------------------------------------------
__global__ __launch_bounds__(256) void resolve_hist_k(const float* __restrict__ un,
                                                      const unsigned* __restrict__ excl,
                                                      uint2* __restrict__ list,
                                                      const int* __restrict__ gcount,
                                                      int* __restrict__ row_cnt) {
  int t = blockIdx.x * 256 + threadIdx.x;
  int n = min(*gcount, LISTCAP);
  if (t >= n) return;
  uint2 e = list[t];
  int i = e.x >> 13, j = e.x & 8191;
  unsigned word = excl[(size_t)i * 256 + (j >> 5)];
  bool alive = !(i == j || ((word >> (j & 31)) & 1u));
  float v = __uint_as_float(e.y);
  if (alive && v <= COS_THR + EPS_SEL) {   // borderline: decide exactly
    const float* a = un + (size_t)i * DIMS;
    const float* b = un + (size_t)j * DIMS;
    float s = 0.f;
    for (int k = 0; k < DIMS; ++k) s = fmaf(a[k], b[k], s);
    alive = (s > COS_THR);
    if (alive) list[t] = make_uint2(e.x, __float_as_uint(s));
  }
  if (!alive) list[t] = make_uint2(DEADKEY, 0u);
  else        atomicAdd(&row_cnt[i], 1);
}

// 4) exclusive scan over 8192 row counts (single block)
__global__ __launch_bounds__(256) void scan8k(const int* __restrict__ cnt,
                                              int* __restrict__ off) {
  __shared__ int sm[256];
  int t = threadIdx.x;
  int base = t * 32;
  int s = 0;
  for (int i = 0; i < 32; ++i) s += cnt[base + i];
  sm[t] = s;
  __syncthreads();
  int x = s;
  for (int d = 1; d < 256; d <<= 1) {
    int y = (t >= d) ? sm[t - d] : 0;
    __syncthreads();
    x += y;
    sm[t] = x;
    __syncthreads();
  }
  int run = x - s;
  for (int i = 0; i < 32; ++i) { off[base + i] = run; run += cnt[base + i]; }
  if (t == 255) off[N_USERS] = x;
}

// 5) scatter + pad (fused)
__global__ __launch_bounds__(256) void scatter_pad_k(const uint2* __restrict__ list,
                                                     const int* __restrict__ gcount,
                                                     const int* __restrict__ row_off,
                                                     int* __restrict__ row_pos,
                                                     int* __restrict__ cand_i,
                                                     int* __restrict__ cand_j,
                                                     float* __restrict__ cand_v) {
  int t = blockIdx.x * 256 + threadIdx.x;
  int n = min(*gcount, LISTCAP);
  int M = row_off[N_USERS];
  if (t < n) {
    uint2 e = list[t];
    if (e.x != DEADKEY) {
      int i = e.x >> 13, j = e.x & 8191;
      int pos = row_off[i] + atomicAdd(&row_pos[i], 1);
      if (pos < KCAND) {
        cand_i[pos] = i;
        cand_j[pos] = j;
        cand_v[pos] = __uint_as_float(e.y);
      }
    }
  }
  if (t >= M && t < KCAND) { cand_i[t] = 0; cand_j[t] = 0; cand_v[t] = -1.0f; }
}

// 6) sort each row's span ascending by j
__global__ __launch_bounds__(256) void sortrow_k(const int* __restrict__ row_off,
                                                 const int* __restrict__ row_cnt,
                                                 int* __restrict__ cand_j,
                                                 float* __restrict__ cand_v) {
  int r = blockIdx.x * 256 + threadIdx.x;
  if (r >= N_USERS) return;
  int o = row_off[r], c = row_cnt[r];
  if (o + c > KCAND) c = max(0, KCAND - o);
  for (int a = 1; a < c; ++a) {
    int jv = cand_j[o + a];
    float vv = cand_v[o + a];
    int b = a - 1;
    while (b >= 0 && cand_j[o + b] > jv) {
      cand_j[o + b + 1] = cand_j[o + b];
      cand_v[o + b + 1] = cand_v[o + b];
      --b;
    }
    cand_j[o + b + 1] = jv;
    cand_v[o + b + 1] = vv;
  }
}

// 7) finalize (split logits + exact-chain fallback near ties)
__global__ __launch_bounds__(256) void finalize_k(const float* __restrict__ ue,
                                                  const float* __restrict__ W,
                                                  const float* __restrict__ b,
                                                  const float* __restrict__ g,
                                                  const int* __restrict__ nz,
                                                  const int* __restrict__ cand_i,
                                                  const int* __restrict__ cand_j,
                                                  const float* __restrict__ cand_v,
                                                  const float4* __restrict__ P,
                                                  float* __restrict__ out) {
  int p = blockIdx.x * 256 + threadIdx.x;
  if (p >= NTOT) return;

  int i, j;
  float wgt;
  if (p < EDGES) {
    i = nz[2 * p];
    j = nz[2 * p + 1];
    wgt = 1.0f;
  } else {
    int q = p - EDGES;
    i = cand_i[q];
    j = cand_j[q];
    wgt = fmaxf(cand_v[q], 0.0f);
  }

  float4 Pi = P[i], Pj = P[j];
  float l0 = Pi.x + Pj.y + b[0];
  float l1 = Pi.z + Pj.w + b[1];
  float g0 = g[2 * p], g1 = g[2 * p + 1];
  float s0 = l0 + g0, s1 = l1 + g1;

  if (fabsf(s0 - s1) < LOGIT_MARGIN) {
    const float* ri = ue + (size_t)i * DIMS;
    const float* rj = ue + (size_t)j * DIMS;
    float e0 = 0.f, e1 = 0.f;
    for (int k = 0; k < DIMS; ++k) {
      e0 = fmaf(ri[k], W[k], e0);
      e1 = fmaf(ri[k], W[256 + k], e1);
    }
    for (int k = 0; k < DIMS; ++k) {
      e0 = fmaf(rj[k], W[128 + k], e0);
      e1 = fmaf(rj[k], W[384 + k], e1);
    }
    s0 = (e0 + b[0]) + g0;
    s1 = (e1 + b[1]) + g1;
  }

  float w = (s0 >= s1) ? wgt : 0.0f;

  out[p] = w;
  out[NTOT + p] = w;
  out[2 * NTOT + p] = w;
  out[3 * NTOT + 2 * p + 0] = (float)i;
  out[3 * NTOT + 2 * p + 1] = (float)j;
}

// ---------------------------------------------------------------------------
extern "C" void kernel_launch(void* const* d_in, const int* in_sizes, int n_in,
                              void* d_out, int out_size, void* d_ws, size_t ws_size,
                              hipStream_t stream) {
  (void)in_sizes; (void)n_in; (void)out_size; (void)ws_size;

  const float* user_emb = (const float*)d_in[0];
  const float* W        = (const float*)d_in[1];
  const float* b        = (const float*)d_in[2];
  const float* gnoise   = (const float*)d_in[3];
  const int*   nz       = (const int*)d_in[4];
  float* out = (float*)d_out;

  char* ws = (char*)d_ws;
  float*          un      = (float*)(ws + 0);                        // 4 MB
  unsigned short* u0      = (unsigned short*)(ws + (4u << 20));      // 2 MB
  unsigned*       excl    = (unsigned*)(ws + (6u << 20));            // 8 MB
  // zeroed region directly after excl: gcount | row_cnt | row_pos
  char*           zbase   = ws + (14u << 20);
  int*            gcount  = (int*)(zbase);                           // 64 B slot
  int*            row_cnt = (int*)(zbase + 64);                      // 32 KB
  int*            row_pos = (int*)(zbase + 64 + 32768);              // 32 KB
  int*            row_off = (int*)(ws + (14u << 20) + (96u << 10));  // 32.8 KB
  uint2*          list    = (uint2*)(ws + (15u << 20));              // 1 MB
  int*            cand_i  = (int*)(ws + (16u << 20));                // 512 KB
  int*            cand_j  = (int*)(ws + (16u << 20) + (512u << 10)); // 512 KB
  float*          cand_v  = (float*)(ws + (17u << 20));              // 512 KB
  float4*         P       = (float4*)(ws + (17u << 20) + (512u << 10)); // 128 KB

  // one memset: excl (8 MB) + counter region (96 KB) are contiguous
  hipMemsetAsync(excl, 0, (8u << 20) + (96u << 10), stream);

  prep_k<<<32 + EDGES / 256, 256, 0, stream>>>(user_emb, W, nz, un, u0, P, excl);
  mfma_pass<<<256, 512, 0, stream>>>(u0, list, gcount);
  resolve_hist_k<<<LISTCAP / 256, 256, 0, stream>>>(un, excl, list, gcount,
                                                    row_cnt);
  scan8k<<<1, 256, 0, stream>>>(row_cnt, row_off);
  scatter_pad_k<<<KCAND / 256, 256, 0, stream>>>(list, gcount, row_off, row_pos,
                                                 cand_i, cand_j, cand_v);
  sortrow_k<<<N_USERS / 256, 256, 0, stream>>>(row_off, row_cnt, cand_j, cand_v);
  finalize_k<<<NTOT / 256, 256, 0, stream>>>(user_emb, W, b, gnoise, nz,
                                             cand_i, cand_j, cand_v, P, out);
}

// Round 11
// 162.168 us; speedup vs baseline: 1.2560x; 1.2560x over previous
//
#include <hip/hip_runtime.h>
#include <hip/hip_bf16.h>
#include <math.h>

#define N_USERS 8192
#define DIMS    128
#define EDGES   262144
#define KCAND   131072
#define NTOT    (EDGES + KCAND)      // 393216
#define LISTCAP 131072
#define CAPB    512                  // per-block LDS staging capacity (entries)
#define NTILES  2080                 // triangular 64x64 tiles of 128x128
#define COS_THR 0.3f
#define EPS_SEL 6e-3f                // > hard error bound ~4e-3 of bf16 cos
#define LOGIT_MARGIN 2e-3f
#define DEADKEY 0xFFFFFFFFu

typedef short bf16x8 __attribute__((ext_vector_type(8)));
typedef float f32x4  __attribute__((ext_vector_type(4)));

// u0 tiled layout: slab (i>>7) of 16384 shorts; within slab:
//   [cq = k>>3 (16)][row = i&127 (128)][k&7 (8)]
// -> each slab is 32 KB contiguous and byte-identical to the LDS As/Bs image.

// ---------------------------------------------------------------------------
// 1) prep (fused): blocks 0..31 -> normalize (bit-exact vs numpy) + tiled
//    bf16 copy + per-user partial logits; blocks 32..1055 -> excl bitmask.
// ---------------------------------------------------------------------------
__global__ __launch_bounds__(256) void prep_k(const float* __restrict__ x,
                                              const float* __restrict__ W,
                                              const int* __restrict__ nz,
                                              float* __restrict__ un,
                                              unsigned short* __restrict__ u0,
                                              float4* __restrict__ P,
                                              unsigned* __restrict__ excl) {
  if (blockIdx.x < 32) {
#pragma clang fp contract(off)
    int i = blockIdx.x * 256 + threadIdx.x;
    const float* r = x + (size_t)i * DIMS;
    float a[8];
#pragma unroll
    for (int j = 0; j < 8; ++j) { float t = r[j]; a[j] = t * t; }
    for (int b8 = 8; b8 < DIMS; b8 += 8) {
#pragma unroll
      for (int j = 0; j < 8; ++j) { float t = r[b8 + j]; a[j] = a[j] + t * t; }
    }
    float s = ((a[0] + a[1]) + (a[2] + a[3])) + ((a[4] + a[5]) + (a[6] + a[7]));
    float n = (float)sqrt((double)s);
    n = fmaxf(n, 1e-12f);
    // tiled bf16 emission: 16 coalesced uint4 stores (one per cq plane)
    unsigned short* slab = u0 + (size_t)(i >> 7) * 16384 + (i & 127) * 8;
#pragma unroll
    for (int cq = 0; cq < 16; ++cq) {
      unsigned short tmp[8];
#pragma unroll
      for (int t = 0; t < 8; ++t) {
        float v = r[cq * 8 + t] / n;
        un[(size_t)i * DIMS + cq * 8 + t] = v;
        __hip_bfloat16 h = __float2bfloat16(v);
        tmp[t] = *(unsigned short*)&h;
      }
      *(uint4*)(slab + (size_t)cq * 1024) = *(uint4*)tmp;
    }
    float a0 = 0.f, b0 = 0.f, a1 = 0.f, b1 = 0.f;
    for (int k = 0; k < DIMS; ++k) {
      float t = r[k];
      a0 = fmaf(t, W[k], a0);
      b0 = fmaf(t, W[128 + k], b0);
      a1 = fmaf(t, W[256 + k], a1);
      b1 = fmaf(t, W[384 + k], b1);
    }
    P[i] = make_float4(a0, b0, a1, b1);
  } else {
    int t = (blockIdx.x - 32) * 256 + threadIdx.x;
    if (t < EDGES) {
      int i = nz[2 * t], j = nz[2 * t + 1];
      atomicOr(&excl[(size_t)i * 256 + (j >> 5)], 1u << (j & 31));
    }
  }
}

// ---------------------------------------------------------------------------
// 2) mfma_pass: 128x128 tiles, triangular (bJ >= bI, 2080 independent blocks
//    of 512 — R10 post-mortem: persistence at 1 block/CU regressed; 2/CU
//    independent blocks hide latency better).  Single-shot K staging, ONE
//    barrier (R9-verified).  NEW: u0 is pre-tiled, so staging loads are flat
//    coalesced slab copies (R9/R10 loads were stride-256B gathers touching
//    64 lines/instr — the 4x latency amplification this removes).
//    Wave tile 32x64, acc 32 VGPR (no-spill budget, R8/R9-verified).
//    Emit j>i + mirror; LDS list; ONE global atomicAdd per block.
// ---------------------------------------------------------------------------
__global__ __launch_bounds__(512) void mfma_pass(const unsigned short* __restrict__ u0,
                                                 uint2* __restrict__ list,
                                                 int* __restrict__ gcount) {
  __shared__ __align__(16) unsigned short As[4][4][128][8];  // 32 KB
  __shared__ __align__(16) unsigned short Bs[4][4][128][8];  // 32 KB
  __shared__ uint2 svec[CAPB];                               // 4 KB
  __shared__ int lcnt, lbase;

  const int tid  = threadIdx.x;
  const int lane = tid & 63;
  const int wv   = tid >> 6;
  const int quad = lane >> 4;
  const int l15  = lane & 15;

  // triangular decode: (bi, bj) with bj >= bi over 64 tiles of 128
  int rem = blockIdx.x, bi = 0;
  while (rem >= 64 - bi) { rem -= 64 - bi; ++bi; }
  const int bj = bi + rem;
  const int I0 = bi * 128, J0 = bj * 128;
  const int moff = (wv & 3) * 32, noff = (wv >> 2) * 64;

  if (tid == 0) lcnt = 0;

  // ---- single-shot staging: flat coalesced slab copy (memcpy semantics) ----
  const uint4* __restrict__ Aslab = (const uint4*)(u0 + (size_t)bi * 16384);
  const uint4* __restrict__ Bslab = (const uint4*)(u0 + (size_t)bj * 16384);
  uint4 pA[4], pB[4];
#pragma unroll
  for (int it = 0; it < 4; ++it) {
    pA[it] = Aslab[it * 512 + tid];
    pB[it] = Bslab[it * 512 + tid];
  }
#pragma unroll
  for (int it = 0; it < 4; ++it) {
    ((uint4*)As)[it * 512 + tid] = pA[it];
    ((uint4*)Bs)[it * 512 + tid] = pB[it];
  }
  __syncthreads();   // the ONLY barrier before the epilogue

  f32x4 acc[2][4];
#pragma unroll
  for (int mt = 0; mt < 2; ++mt)
#pragma unroll
    for (int nt = 0; nt < 4; ++nt)
#pragma unroll
      for (int g = 0; g < 4; ++g) acc[mt][nt][g] = 0.f;

  // ---- K loop: 4 kc x (2 af + 4 bfr b128 reads, 8 MFMAs), no barriers ----
#pragma unroll
  for (int kc = 0; kc < 4; ++kc) {
    bf16x8 af[2], bfr[4];
#pragma unroll
    for (int mt = 0; mt < 2; ++mt)
      af[mt] = *(const bf16x8*)&As[kc][quad][moff + mt * 16 + l15][0];
#pragma unroll
    for (int nt = 0; nt < 4; ++nt)
      bfr[nt] = *(const bf16x8*)&Bs[kc][quad][noff + nt * 16 + l15][0];
#pragma unroll
    for (int mt = 0; mt < 2; ++mt)
#pragma unroll
      for (int nt = 0; nt < 4; ++nt)
        acc[mt][nt] = __builtin_amdgcn_mfma_f32_16x16x32_bf16(
            af[mt], bfr[nt], acc[mt][nt], 0, 0, 0);
  }

  // ---- epilogue: j > i only; emit pair + mirror (one LDS atomic) ----
#pragma unroll
  for (int mt = 0; mt < 2; ++mt)
#pragma unroll
    for (int nt = 0; nt < 4; ++nt)
#pragma unroll
      for (int g = 0; g < 4; ++g) {
        float v = acc[mt][nt][g];
        if (v > COS_THR - EPS_SEL) {
          int i = I0 + moff + mt * 16 + quad * 4 + g;
          int j = J0 + noff + nt * 16 + l15;
          if (j > i) {
            int idx = atomicAdd(&lcnt, 2);
            if (idx + 1 < CAPB) {
              svec[idx]     = make_uint2(((unsigned)i << 13) | j,
                                         __float_as_uint(v));
              svec[idx + 1] = make_uint2(((unsigned)j << 13) | i,
                                         __float_as_uint(v));
            }
          }
        }
      }

  __syncthreads();
  int n = min(lcnt, CAPB);
  if (tid == 0) lbase = atomicAdd(gcount, n);
  __syncthreads();
  int base = lbase;
  for (int t = tid; t < n; t += 512) {
    int o = base + t;
    if (o < LISTCAP) list[o] = svec[t];
  }
}

// ---------------------------------------------------------------------------
// 3) resolve + histogram (fused)
// ---------------------------------------------------------------------------
__global__ __launch_bounds__(256) void resolve_hist_k(const float* __restrict__ un,
                                                      const unsigned* __restrict__ excl,
                                                      uint2* __restrict__ list,
                                                      const int* __restrict__ gcount,
                                                      int* __restrict__ row_cnt) {
  int t = blockIdx.x * 256 + threadIdx.x;
  int n = min(*gcount, LISTCAP);
  if (t >= n) return;
  uint2 e = list[t];
  int i = e.x >> 13, j = e.x & 8191;
  unsigned word = excl[(size_t)i * 256 + (j >> 5)];
  bool alive = !(i == j || ((word >> (j & 31)) & 1u));
  float v = __uint_as_float(e.y);
  if (alive && v <= COS_THR + EPS_SEL) {   // borderline: decide exactly
    const float* a = un + (size_t)i * DIMS;
    const float* b = un + (size_t)j * DIMS;
    float s = 0.f;
    for (int k = 0; k < DIMS; ++k) s = fmaf(a[k], b[k], s);
    alive = (s > COS_THR);
    if (alive) list[t] = make_uint2(e.x, __float_as_uint(s));
  }
  if (!alive) list[t] = make_uint2(DEADKEY, 0u);
  else        atomicAdd(&row_cnt[i], 1);
}

// 4) exclusive scan over 8192 row counts (single block)
__global__ __launch_bounds__(256) void scan8k(const int* __restrict__ cnt,
                                              int* __restrict__ off) {
  __shared__ int sm[256];
  int t = threadIdx.x;
  int base = t * 32;
  int s = 0;
  for (int i = 0; i < 32; ++i) s += cnt[base + i];
  sm[t] = s;
  __syncthreads();
  int x = s;
  for (int d = 1; d < 256; d <<= 1) {
    int y = (t >= d) ? sm[t - d] : 0;
    __syncthreads();
    x += y;
    sm[t] = x;
    __syncthreads();
  }
  int run = x - s;
  for (int i = 0; i < 32; ++i) { off[base + i] = run; run += cnt[base + i]; }
  if (t == 255) off[N_USERS] = x;
}

// 5) scatter + pad (fused)
__global__ __launch_bounds__(256) void scatter_pad_k(const uint2* __restrict__ list,
                                                     const int* __restrict__ gcount,
                                                     const int* __restrict__ row_off,
                                                     int* __restrict__ row_pos,
                                                     int* __restrict__ cand_i,
                                                     int* __restrict__ cand_j,
                                                     float* __restrict__ cand_v) {
  int t = blockIdx.x * 256 + threadIdx.x;
  int n = min(*gcount, LISTCAP);
  int M = row_off[N_USERS];
  if (t < n) {
    uint2 e = list[t];
    if (e.x != DEADKEY) {
      int i = e.x >> 13, j = e.x & 8191;
      int pos = row_off[i] + atomicAdd(&row_pos[i], 1);
      if (pos < KCAND) {
        cand_i[pos] = i;
        cand_j[pos] = j;
        cand_v[pos] = __uint_as_float(e.y);
      }
    }
  }
  if (t >= M && t < KCAND) { cand_i[t] = 0; cand_j[t] = 0; cand_v[t] = -1.0f; }
}

// 6) sort each row's span ascending by j
__global__ __launch_bounds__(256) void sortrow_k(const int* __restrict__ row_off,
                                                 const int* __restrict__ row_cnt,
                                                 int* __restrict__ cand_j,
                                                 float* __restrict__ cand_v) {
  int r = blockIdx.x * 256 + threadIdx.x;
  if (r >= N_USERS) return;
  int o = row_off[r], c = row_cnt[r];
  if (o + c > KCAND) c = max(0, KCAND - o);
  for (int a = 1; a < c; ++a) {
    int jv = cand_j[o + a];
    float vv = cand_v[o + a];
    int b = a - 1;
    while (b >= 0 && cand_j[o + b] > jv) {
      cand_j[o + b + 1] = cand_j[o + b];
      cand_v[o + b + 1] = cand_v[o + b];
      --b;
    }
    cand_j[o + b + 1] = jv;
    cand_v[o + b + 1] = vv;
  }
}

// 7) finalize (split logits + exact-chain fallback near ties)
__global__ __launch_bounds__(256) void finalize_k(const float* __restrict__ ue,
                                                  const float* __restrict__ W,
                                                  const float* __restrict__ b,
                                                  const float* __restrict__ g,
                                                  const int* __restrict__ nz,
                                                  const int* __restrict__ cand_i,
                                                  const int* __restrict__ cand_j,
                                                  const float* __restrict__ cand_v,
                                                  const float4* __restrict__ P,
                                                  float* __restrict__ out) {
  int p = blockIdx.x * 256 + threadIdx.x;
  if (p >= NTOT) return;

  int i, j;
  float wgt;
  if (p < EDGES) {
    i = nz[2 * p];
    j = nz[2 * p + 1];
    wgt = 1.0f;
  } else {
    int q = p - EDGES;
    i = cand_i[q];
    j = cand_j[q];
    wgt = fmaxf(cand_v[q], 0.0f);
  }

  float4 Pi = P[i], Pj = P[j];
  float l0 = Pi.x + Pj.y + b[0];
  float l1 = Pi.z + Pj.w + b[1];
  float g0 = g[2 * p], g1 = g[2 * p + 1];
  float s0 = l0 + g0, s1 = l1 + g1;

  if (fabsf(s0 - s1) < LOGIT_MARGIN) {
    const float* ri = ue + (size_t)i * DIMS;
    const float* rj = ue + (size_t)j * DIMS;
    float e0 = 0.f, e1 = 0.f;
    for (int k = 0; k < DIMS; ++k) {
      e0 = fmaf(ri[k], W[k], e0);
      e1 = fmaf(ri[k], W[256 + k], e1);
    }
    for (int k = 0; k < DIMS; ++k) {
      e0 = fmaf(rj[k], W[128 + k], e0);
      e1 = fmaf(rj[k], W[384 + k], e1);
    }
    s0 = (e0 + b[0]) + g0;
    s1 = (e1 + b[1]) + g1;
  }

  float w = (s0 >= s1) ? wgt : 0.0f;

  out[p] = w;
  out[NTOT + p] = w;
  out[2 * NTOT + p] = w;
  out[3 * NTOT + 2 * p + 0] = (float)i;
  out[3 * NTOT + 2 * p + 1] = (float)j;
}

// ---------------------------------------------------------------------------
extern "C" void kernel_launch(void* const* d_in, const int* in_sizes, int n_in,
                              void* d_out, int out_size, void* d_ws, size_t ws_size,
                              hipStream_t stream) {
  (void)in_sizes; (void)n_in; (void)out_size; (void)ws_size;

  const float* user_emb = (const float*)d_in[0];
  const float* W        = (const float*)d_in[1];
  const float* b        = (const float*)d_in[2];
  const float* gnoise   = (const float*)d_in[3];
  const int*   nz       = (const int*)d_in[4];
  float* out = (float*)d_out;

  char* ws = (char*)d_ws;
  float*          un      = (float*)(ws + 0);                        // 4 MB
  unsigned short* u0      = (unsigned short*)(ws + (4u << 20));      // 2 MB (tiled)
  unsigned*       excl    = (unsigned*)(ws + (6u << 20));            // 8 MB
  // zeroed region directly after excl: gcount | row_cnt | row_pos
  char*           zbase   = ws + (14u << 20);
  int*            gcount  = (int*)(zbase);                           // 64 B slot
  int*            row_cnt = (int*)(zbase + 64);                      // 32 KB
  int*            row_pos = (int*)(zbase + 64 + 32768);              // 32 KB
  int*            row_off = (int*)(ws + (14u << 20) + (96u << 10));  // 32.8 KB
  uint2*          list    = (uint2*)(ws + (15u << 20));              // 1 MB
  int*            cand_i  = (int*)(ws + (16u << 20));                // 512 KB
  int*            cand_j  = (int*)(ws + (16u << 20) + (512u << 10)); // 512 KB
  float*          cand_v  = (float*)(ws + (17u << 20));              // 512 KB
  float4*         P       = (float4*)(ws + (17u << 20) + (512u << 10)); // 128 KB

  // one memset: excl (8 MB) + counter region (96 KB) are contiguous
  hipMemsetAsync(excl, 0, (8u << 20) + (96u << 10), stream);

  prep_k<<<32 + EDGES / 256, 256, 0, stream>>>(user_emb, W, nz, un, u0, P, excl);
  mfma_pass<<<NTILES, 512, 0, stream>>>(u0, list, gcount);
  resolve_hist_k<<<LISTCAP / 256, 256, 0, stream>>>(un, excl, list, gcount,
                                                    row_cnt);
  scan8k<<<1, 256, 0, stream>>>(row_cnt, row_off);
  scatter_pad_k<<<KCAND / 256, 256, 0, stream>>>(list, gcount, row_off, row_pos,
                                                 cand_i, cand_j, cand_v);
  sortrow_k<<<N_USERS / 256, 256, 0, stream>>>(row_off, row_cnt, cand_j, cand_v);
  finalize_k<<<NTOT / 256, 256, 0, stream>>>(user_emb, W, b, gnoise, nz,
                                             cand_i, cand_j, cand_v, P, out);
}